// Round 8
// baseline (1444.396 us; speedup 1.0000x reference)
//
#include <hip/hip_runtime.h>
#include <cstdint>
#include <cstddef>

typedef __attribute__((ext_vector_type(4))) int int32x4;
typedef __attribute__((ext_vector_type(16))) int int32x16;

#define DEVI __device__ __forceinline__

constexpr int M = 16384;
constexpr int N = 11008;
constexpr int K = 4096;
constexpr int BM = 256, BN = 128, BK = 64;   // BK in int8 elements (= bytes)
constexpr int NT_M = M / BM;                 // 64
constexpr int NT_N = N / BN;                 // 86
constexpr int NTILES = K / BK;               // 64
constexpr int NWG = NT_M * NT_N;             // 5504 = 8 * 688 (exact)
constexpr int A_BYTES = BM * BK;             // 16 KB
constexpr int B_BYTES = BN * BK;             // 8 KB
constexpr int SLOT = A_BYTES + B_BYTES;      // 24 KB -> ring-2 = 48 KiB LDS

DEVI void gload_lds16(const void* gsrc, void* ldst) {
  __builtin_amdgcn_global_load_lds(
      (const __attribute__((address_space(1))) unsigned int*)gsrc,
      (__attribute__((address_space(3))) unsigned int*)ldst,
      16, 0, 0);
}

// ---- weight repack: int32 (harness int convention) -> int8 ----
__global__ __launch_bounds__(256) void pack_w_kernel(const int* __restrict__ w32,
                                                     signed char* __restrict__ w8) {
  const int idx = blockIdx.x * 256 + threadIdx.x;
  const int total4 = N * K / 4;
  if (idx < total4) {
    const int4 v = ((const int4*)w32)[idx];
    ((int*)w8)[idx] = (v.x & 255) | ((v.y & 255) << 8) |
                      ((v.z & 255) << 16) | ((v.w & 255) << 24);
  }
}

// ---- per-row symmetric int8 quantization of X ----
__global__ __launch_bounds__(256) void quant_x_kernel(const float* __restrict__ x,
                                                      signed char* __restrict__ xq,
                                                      float* __restrict__ sx) {
  const int row = blockIdx.x;
  const int t = threadIdx.x;
  const float4* xr = (const float4*)(x + (size_t)row * K);
  float4 v[4];
  float amax = 0.f;
  #pragma unroll
  for (int c = 0; c < 4; ++c) {
    v[c] = xr[c * 256 + t];
    amax = fmaxf(amax, fmaxf(fmaxf(fabsf(v[c].x), fabsf(v[c].y)),
                             fmaxf(fabsf(v[c].z), fabsf(v[c].w))));
  }
  __shared__ float red[256];
  red[t] = amax;
  __syncthreads();
  #pragma unroll
  for (int s = 128; s >= 1; s >>= 1) {
    if (t < s) red[t] = fmaxf(red[t], red[t + s]);
    __syncthreads();
  }
  const float am = fmaxf(red[0], 1e-20f);
  const float inv = 127.f / am;
  if (t == 0) sx[row] = am * (1.f / 127.f);
  int* xq32 = (int*)(xq + (size_t)row * K);
  #pragma unroll
  for (int c = 0; c < 4; ++c) {
    int q0 = min(127, max(-127, __float2int_rn(v[c].x * inv)));
    int q1 = min(127, max(-127, __float2int_rn(v[c].y * inv)));
    int q2 = min(127, max(-127, __float2int_rn(v[c].z * inv)));
    int q3 = min(127, max(-127, __float2int_rn(v[c].w * inv)));
    xq32[c * 256 + t] = (q0 & 255) | ((q1 & 255) << 8) |
                        ((q2 & 255) << 16) | ((q3 & 255) << 24);
  }
}

// ---- 256x128 int8 GEMM, ring-2 dbuf (48 KiB LDS -> 2 blocks/CU) ----
// 4 waves, wave tile 128x64 (4x2 frags of 32x32, acc = 128 AGPR) — identical
// per-wave structure to round 6; the change is 2 INDEPENDENT blocks per CU
// so one block's MFMA fills the other's vmcnt/barrier gaps (m97/m114 TLP).
// Classic dbuf: STAGE(t+1) at tile top; vmcnt(0)+barrier at tile bottom.
// LDS slot: A 16 KB (plane*4096 + row*16, plane 0..3) then B 8 KB
// (plane*2048 + row*16). gload_lds dest = chunk*16 (linear).
__global__ __launch_bounds__(256, 2) void gemm_i8_kernel(const signed char* __restrict__ aq,
                                                         const signed char* __restrict__ wq,
                                                         const float* __restrict__ sx,
                                                         const float* __restrict__ sw,
                                                         float* __restrict__ out) {
  __shared__ __align__(16) signed char smem[2 * SLOT];   // 48 KiB

  const int t = threadIdx.x;       // 0..255
  const int w = t >> 6;            // wave 0..3
  const int l = t & 63;

  // XCD-aware swizzle (bijective: 5504 % 8 == 0).
  const int bid = blockIdx.x;
  const int wg = (bid & 7) * (NWG / 8) + (bid >> 3);
  const int mt = wg / NT_N;
  const int nt = wg % NT_N;
  const int m0 = mt * BM, n0 = nt * BN;

  // Staging: 6 x 16B chunks per thread per tile (4 A + 2 B).
  // A chunks: q = c*256 + t (c=0..3): plane = c, row = t.
  // B chunks: q = c*256 + t (c=0..1): plane = (q>>7)&3, row = t&127.
  const signed char* srcA[4];
  const signed char* srcB[2];
  #pragma unroll
  for (int c = 0; c < 4; ++c)
    srcA[c] = aq + (size_t)(m0 + t) * K + c * 16;
  #pragma unroll
  for (int c = 0; c < 2; ++c) {
    const int q = c * 256 + t;
    srcB[c] = wq + (size_t)(n0 + (q & 127)) * K + (q >> 7) * 16;
  }
  const int dBase = (t & ~63) * 16;      // wave-uniform; HW adds lane*16

#define STAGE(tile)                                                           \
  {                                                                           \
    signed char* sb = smem + ((tile) & 1) * SLOT;                             \
    const int ko = (tile) * BK;                                               \
    gload_lds16(srcA[0] + ko, sb + dBase);                                    \
    gload_lds16(srcA[1] + ko, sb + 4096 + dBase);                             \
    gload_lds16(srcA[2] + ko, sb + 8192 + dBase);                             \
    gload_lds16(srcA[3] + ko, sb + 12288 + dBase);                            \
    gload_lds16(srcB[0] + ko, sb + 16384 + dBase);                            \
    gload_lds16(srcB[1] + ko, sb + 20480 + dBase);                            \
  }

  // Wave output: 128x64 at (wm*128, wn*64); 4x2 frags of 32x32.
  const int wm = w >> 1, wn = w & 1;
  const int lk = l >> 5;           // 16B plane within k-step (0/1)
  const int lr = l & 31;
  int aOff[4], bOff[2];
  #pragma unroll
  for (int i = 0; i < 4; ++i)
    aOff[i] = lk * 4096 + (wm * 128 + i * 32 + lr) * 16;            // A: plane stride 4096
  #pragma unroll
  for (int j = 0; j < 2; ++j)
    bOff[j] = 16384 + lk * 2048 + (wn * 64 + j * 32 + lr) * 16;     // B: plane stride 2048

  int32x16 acc[4][2] = {};
  int32x4 af0[4], bf0[2], af1[4], bf1[2];

  // DSL(tile, ks): 6 ds_read_b128 for k-step ks (planes 2ks, 2ks+1).
#define DSL(tile, ks, AF, BF)                                                 \
  {                                                                           \
    const signed char* sb = smem + ((tile) & 1) * SLOT;                       \
    AF[0] = *(const int32x4*)(sb + aOff[0] + (ks) * 8192);                    \
    AF[1] = *(const int32x4*)(sb + aOff[1] + (ks) * 8192);                    \
    AF[2] = *(const int32x4*)(sb + aOff[2] + (ks) * 8192);                    \
    AF[3] = *(const int32x4*)(sb + aOff[3] + (ks) * 8192);                    \
    BF[0] = *(const int32x4*)(sb + bOff[0] + (ks) * 4096);                    \
    BF[1] = *(const int32x4*)(sb + bOff[1] + (ks) * 4096);                    \
  }

#define MFMA8(AF, BF)                                                         \
  __builtin_amdgcn_s_setprio(1);                                              \
  {                                                                           \
    _Pragma("unroll")                                                         \
    for (int i = 0; i < 4; ++i) {                                             \
      acc[i][0] = __builtin_amdgcn_mfma_i32_32x32x32_i8(AF[i], BF[0],         \
                                                        acc[i][0], 0, 0, 0);  \
      acc[i][1] = __builtin_amdgcn_mfma_i32_32x32x32_i8(AF[i], BF[1],         \
                                                        acc[i][1], 0, 0, 0);  \
    }                                                                         \
  }                                                                           \
  __builtin_amdgcn_s_setprio(0);

#define WAITV(n) asm volatile("s_waitcnt vmcnt(" #n ")" ::: "memory");
#define WLGKM(n)                                                              \
  asm volatile("s_waitcnt lgkmcnt(" #n ")" ::: "memory");                     \
  __builtin_amdgcn_sched_barrier(0);
#define BAR() __builtin_amdgcn_s_barrier();

  // Prologue: stage tile 0, certify, publish.
  STAGE(0)
  WAITV(0)
  BAR()

  // Main loop: per tile {STAGE(t+1); 12 reads; lgkm(6); MFMA; lgkm(0); MFMA;
  // vmcnt(0); BAR}. The vmcnt(0) drain is covered by the co-resident block.
  #pragma unroll 2
  for (int tt = 0; tt < 63; ++tt) {
    STAGE(tt + 1)            // writes other slot (tile tt-1 retired at last BAR)
    DSL(tt, 0, af0, bf0)
    DSL(tt, 1, af1, bf1)
    WLGKM(6)                 // k-step 0 frags ready; k-step 1 in flight
    MFMA8(af0, bf0)
    WLGKM(0)                 // k-step 1 frags ready
    MFMA8(af1, bf1)
    WAITV(0)                 // tile tt+1 landed (all 6 of this thread's loads)
    BAR()                    // publish tt+1; retire all reads of tt
  }
  // Final tile 63: no staging.
  DSL(63, 0, af0, bf0)
  DSL(63, 1, af1, bf1)
  WLGKM(6)
  MFMA8(af0, bf0)
  WLGKM(0)
  MFMA8(af1, bf1)

  // Epilogue: dequant + store.
  // 32x32 C/D map: col = lane&31, row = (r&3) + 8*(r>>2) + 4*(lane>>5).
  const int rbase = lk * 4;
  float swv[2];
  #pragma unroll
  for (int fj = 0; fj < 2; ++fj) swv[fj] = sw[n0 + wn * 64 + fj * 32 + lr];
  #pragma unroll
  for (int fi = 0; fi < 4; ++fi) {
    #pragma unroll
    for (int r = 0; r < 16; ++r) {
      const int row = (r & 3) + 8 * (r >> 2) + rbase;
      const int grow = m0 + wm * 128 + fi * 32 + row;
      const float sxv = sx[grow];
      float* orow = out + (size_t)grow * N + n0 + wn * 64 + lr;
      #pragma unroll
      for (int fj = 0; fj < 2; ++fj) {
        orow[fj * 32] = (float)acc[fi][fj][r] * sxv * swv[fj];
      }
    }
  }
}

extern "C" void kernel_launch(void* const* d_in, const int* in_sizes, int n_in,
                              void* d_out, int out_size, void* d_ws, size_t ws_size,
                              hipStream_t stream) {
  const float* x = (const float*)d_in[0];
  const int* w32 = (const int*)d_in[1];
  const float* wscale = (const float*)d_in[2];
  float* out = (float*)d_out;

  signed char* xq = (signed char*)d_ws;
  signed char* wq = xq + (size_t)M * K;
  float* sx = (float*)(wq + (size_t)N * K);

  pack_w_kernel<<<(N * K / 4 + 255) / 256, 256, 0, stream>>>(w32, wq);
  quant_x_kernel<<<M, 256, 0, stream>>>(x, xq, sx);
  gemm_i8_kernel<<<NWG, 256, 0, stream>>>(xq, wq, sx, wscale, out);
}